// Round 1
// baseline (256.524 us; speedup 1.0000x reference)
//
#include <hip/hip_runtime.h>

// HidePatchLayer: out = in * mask, mask[w,h] = (cell_rand[w/16, h/16] > 0.5)
// Shapes: in [256,224,224,3] f32, cell_rand [14,14] f32, grid_size = 16.
// Memory-bound: 308 MB total traffic -> ~49 us at 6.3 TB/s.

#define NCELL 196         // 14*14
#define BLOCK 256

__global__ __launch_bounds__(BLOCK) void hide_patch_kernel(
    const float4* __restrict__ in,
    const float*  __restrict__ cell_rand,
    float4* __restrict__ out,
    unsigned n4)
{
    __shared__ float keep[NCELL];
    const unsigned t = threadIdx.x;
    if (t < NCELL) keep[t] = (cell_rand[t] > 0.5f) ? 1.0f : 0.0f;
    __syncthreads();

    const unsigned i = blockIdx.x * BLOCK + t;
    if (i >= n4) return;

    float4 v = in[i];                 // 16 B/lane coalesced load
    const unsigned base = i * 4u;     // flat float index of v.x

    float m[4];
#pragma unroll
    for (int e = 0; e < 4; ++e) {
        unsigned idx = base + (unsigned)e;
        unsigned hw  = idx / 3u;            // = b*224*224 + w*224 + h
        unsigned h   = hw % 224u;
        unsigned w   = (hw / 224u) % 224u;  // W == H == 224
        m[e] = keep[(w >> 4) * 14u + (h >> 4)];
    }

    v.x *= m[0];
    v.y *= m[1];
    v.z *= m[2];
    v.w *= m[3];
    out[i] = v;                       // 16 B/lane coalesced store
}

extern "C" void kernel_launch(void* const* d_in, const int* in_sizes, int n_in,
                              void* d_out, int out_size, void* d_ws, size_t ws_size,
                              hipStream_t stream)
{
    const float4* in        = (const float4*)d_in[0];   // [256,224,224,3] f32
    const float*  cell_rand = (const float*)d_in[1];    // [14,14] f32
    // d_in[2] is grid_size (=16), baked into the shift constants above.

    float4* out = (float4*)d_out;

    const unsigned n  = (unsigned)in_sizes[0];          // 38,535,168 (divisible by 4)
    const unsigned n4 = n / 4u;

    const unsigned grid = (n4 + BLOCK - 1) / BLOCK;
    hide_patch_kernel<<<grid, BLOCK, 0, stream>>>(in, cell_rand, out, n4);
}

// Round 3
// 245.864 us; speedup vs baseline: 1.0434x; 1.0434x over previous
//
#include <hip/hip_runtime.h>

// HidePatchLayer: out = in * mask, mask[w,h] = (cell_rand[w/16, h/16] > 0.5)
// Shapes: in [256,224,224,3] f32, cell_rand [14,14] f32, grid_size = 16.
//
// Key structure: mask is constant over contiguous 48-float runs
// (fixed b,w,h-cell: 16 h x 3 c), and runs start at multiples of 48 floats,
// so every float4 lies entirely inside one run -> one mask lookup per float4,
// and hidden runs can skip the global load entirely (write exact zeros).
// Traffic: 154 MB write + ~77 MB read (~50% cells kept) ~= 231 MB -> ~37 us.

#define NCELL 196         // 14*14
#define BLOCK 256

// Native clang vector type: __builtin_nontemporal_* rejects HIP_vector_type.
typedef float vfloat4 __attribute__((ext_vector_type(4)));

__global__ __launch_bounds__(BLOCK) void hide_patch_kernel(
    const vfloat4* __restrict__ in,
    const float*   __restrict__ cell_rand,
    vfloat4* __restrict__ out,
    unsigned n4)
{
    __shared__ float keep[NCELL];
    const unsigned t = threadIdx.x;
    if (t < NCELL) keep[t] = (cell_rand[t] > 0.5f) ? 1.0f : 0.0f;
    __syncthreads();

    const unsigned i = blockIdx.x * BLOCK + t;
    if (i >= n4) return;

    // Cell of this float4 (all 4 elements share it; see header comment).
    const unsigned base = i * 4u;
    const unsigned hw   = base / 3u;            // = b*224*224 + w*224 + h
    const unsigned h    = hw % 224u;
    const unsigned w    = (hw / 224u) % 224u;   // W == H == 224
    const float m = keep[(w >> 4) * 14u + (h >> 4)];

    vfloat4 v = (vfloat4)(0.0f);
    if (m != 0.0f) {
        v = __builtin_nontemporal_load(&in[i]);  // fetch only kept cells
    }
    __builtin_nontemporal_store(v, &out[i]);     // streaming store, no reuse
}

extern "C" void kernel_launch(void* const* d_in, const int* in_sizes, int n_in,
                              void* d_out, int out_size, void* d_ws, size_t ws_size,
                              hipStream_t stream)
{
    const vfloat4* in        = (const vfloat4*)d_in[0]; // [256,224,224,3] f32
    const float*   cell_rand = (const float*)d_in[1];   // [14,14] f32
    // d_in[2] is grid_size (=16), baked into the shift constants above.

    vfloat4* out = (vfloat4*)d_out;

    const unsigned n  = (unsigned)in_sizes[0];          // 38,535,168 (divisible by 4)
    const unsigned n4 = n / 4u;

    const unsigned grid = (n4 + BLOCK - 1) / BLOCK;
    hide_patch_kernel<<<grid, BLOCK, 0, stream>>>(in, cell_rand, out, n4);
}